// Round 10
// baseline (112.823 us; speedup 1.0000x reference)
//
#include <hip/hip_runtime.h>

// DAS beamforming: out[b,z,x,k] = sum_c lerp(rf[b,c], delay(b,c,z,x))[k]
// Round 10: DIRECT-FROM-CACHE GATHER -- no LDS, no barriers, no staging.
// R1-R9 evidence: das is pinned at ~36-40 us under every barrier-phased LDS
// staging variant (TLP/ILP/width/domains all ~neutral); pipes are ~40% idle
// on barrier convoys, and staging adds 256 MB L2->LDS + 3.4 us/CU LDS-write.
// Here each block gathers straight from global:
//  - chunk = bid & 7 == XCD id (proven by R4's cross-XCD atomic storm), so
//    each XCD's rf working set = 16 ch x 2 batches x 32 KiB = 1 MiB, resident
//    in its private 4-MiB L2; within the channel loop the 32 KiB slice also
//    fits the 32-KiB L1.
//  - 1024 blocks x 512 thr = 4 blocks/CU, 32 waves/CU (no barriers -> block
//    size is free; max TLP to hide L2 latency), 2 px/thread, ~40 VGPR.
//  - epilogue: disjoint partials to ws + reduce (R4: contended atomics
//    ping-pong cross-XCD; R3: never READ pre-poisoned ws data -- partials
//    are write-then-read within one replay).
// Gamble acknowledged: if the texture addresser is rate-limited on 64 random
// 16-B lane requests per wave-load, this loses; revert to R5/R9 next round.

#define NBATCH 2
#define NC 128
#define NS 2048
#define NK 4
#define NM 65536                              // Nz*Nx pixels per batch

#define THREADS 512
#define PX_PER_THREAD 2
#define PX_PER_BLOCK (THREADS * PX_PER_THREAD)   // 1024
#define C_PER_BLOCK 16
#define N_CHUNKS (NC / C_PER_BLOCK)           // 8
#define N_TILES (NM / PX_PER_BLOCK)           // 64
#define NBLOCKS (NBATCH * N_TILES * N_CHUNKS) // 1024 = 4 blocks/CU

#define PART_BYTES ((size_t)N_CHUNKS * NBATCH * NM * NK * 4)  // 16.8 MB

typedef __attribute__((ext_vector_type(4))) float floatv4;

template <bool ATOMIC>
__global__ __launch_bounds__(THREADS, 8) void das_kernel(
    const float* __restrict__ rf, const float* __restrict__ g,
    const float* __restrict__ pr, const float* __restrict__ p,
    float* __restrict__ dst)    // ATOMIC ? out : partials in ws
{
    const int bid   = blockIdx.x;
    const int chunk = bid & (N_CHUNKS - 1);   // == XCD id: L2-pins rf chunk
    const int tile  = (bid >> 3) & (N_TILES - 1);
    const int b     = bid >> 9;
    const int t     = threadIdx.x;
    const int px0   = tile * PX_PER_BLOCK;

    const float c0v = p[b * 4 + 0];
    const float fsv = p[b * 4 + 1];
    const float t0v = p[b * 4 + 2];
    const float scale = fsv / c0v;            // samples per meter
    const float sb0   = scale * t0v;

    float gx[PX_PER_THREAD], gy[PX_PER_THREAD], gzv[PX_PER_THREAD], sbase[PX_PER_THREAD];
#pragma unroll
    for (int j = 0; j < PX_PER_THREAD; ++j) {
        const int m = px0 + j * THREADS + t;
        const float* gp = g + ((size_t)b * NM + m) * 3;
        gx[j]  = gp[0];
        gy[j]  = gp[1];
        gzv[j] = gp[2];
        sbase[j] = sb0 + scale * gzv[j];      // fs*(t0 + d_tx)/c0 hoisted
    }

    floatv4 acc[PX_PER_THREAD];
#pragma unroll
    for (int j = 0; j < PX_PER_THREAD; ++j) acc[j] = (floatv4)0.0f;

    const int ch0 = chunk * C_PER_BLOCK;
    const floatv4* slice0 = (const floatv4*)(rf + (size_t)(b * NC + ch0) * NS * NK);

    for (int cc = 0; cc < C_PER_BLOCK; ++cc) {
        // pr pointer/index are block-uniform -> scalar loads
        const float* prp = pr + ((size_t)(b * NC + ch0 + cc)) * 3;
        const float prx = prp[0], pry = prp[1], prz = prp[2];
        const floatv4* sl = slice0 + (size_t)cc * (NS * NK / 4);

#pragma unroll
        for (int j = 0; j < PX_PER_THREAD; ++j) {
            const float dx = gx[j]  - prx;
            const float dy = gy[j]  - pry;
            const float dz = gzv[j] - prz;
            const float drx = __builtin_amdgcn_sqrtf(fmaf(dx, dx, fmaf(dy, dy, dz * dz)));
            float s = fmaf(scale, drx, sbase[j]);         // frac sample idx
            s = fminf(fmaxf(s, 0.0f), (float)(NS - 1));   // clamp
            const float fi = fminf(floorf(s), (float)(NS - 2));
            const float w  = s - fi;
            const float wm = 1.0f - w;
            const int i0 = (int)fi;
            // two adjacent 16-B loads: global_load_dwordx4 + offset:16,
            // L1-resident slice (32 KiB), XCD-local L2 behind it
            const floatv4 y0 = sl[i0];
            const floatv4 y1 = sl[i0 + 1];
            acc[j] += y0 * wm + y1 * w;                   // packed-f32 friendly
        }
    }

    if (ATOMIC) {
        float* ob = dst + (size_t)b * NM * NK;
#pragma unroll
        for (int j = 0; j < PX_PER_THREAD; ++j) {
            const int m = px0 + j * THREADS + t;
            float* op = ob + (size_t)m * NK;
            atomicAdd(op + 0, acc[j].x);
            atomicAdd(op + 1, acc[j].y);
            atomicAdd(op + 2, acc[j].z);
            atomicAdd(op + 3, acc[j].w);
        }
    } else {
        // partial[chunk][b][m] as float4 — disjoint per block, plain stores
        floatv4* pw = (floatv4*)dst + (size_t)(chunk * NBATCH + b) * NM;
#pragma unroll
        for (int j = 0; j < PX_PER_THREAD; ++j) {
            const int m = px0 + j * THREADS + t;
            pw[m] = acc[j];
        }
    }
}

// out[i] = sum over 8 chunk partials; i indexes float4 over [B*NM)
__global__ __launch_bounds__(256) void reduce_kernel(
    const floatv4* __restrict__ part, floatv4* __restrict__ out)
{
    const int i = blockIdx.x * 256 + threadIdx.x;
    const size_t stride = (size_t)NBATCH * NM;
    floatv4 a = part[i];
#pragma unroll
    for (int c = 1; c < N_CHUNKS; ++c)
        a += part[c * stride + i];
    out[i] = a;
}

extern "C" void kernel_launch(void* const* d_in, const int* in_sizes, int n_in,
                              void* d_out, int out_size, void* d_ws, size_t ws_size,
                              hipStream_t stream) {
    (void)in_sizes; (void)n_in;
    const float* rf = (const float*)d_in[0];
    const float* g  = (const float*)d_in[1];
    const float* pr = (const float*)d_in[2];
    const float* p  = (const float*)d_in[3];
    float* out = (float*)d_out;

    if (ws_size >= PART_BYTES) {
        das_kernel<false><<<NBLOCKS, THREADS, 0, stream>>>(rf, g, pr, p, (float*)d_ws);
        reduce_kernel<<<(NBATCH * NM) / 256, 256, 0, stream>>>((const floatv4*)d_ws,
                                                               (floatv4*)out);
    } else {
        hipMemsetAsync(d_out, 0, (size_t)out_size * sizeof(float), stream);
        das_kernel<true><<<NBLOCKS, THREADS, 0, stream>>>(rf, g, pr, p, out);
    }
}